// Round 2
// baseline (57.413 us; speedup 1.0000x reference)
//
#include <hip/hip_runtime.h>

#define BATCH 4
#define NROWS 2048
#define IN_DIM 1024
#define OUT_DIM 512
#define CH 256                    // chunks per batch
#define R (NROWS / CH)            // 8 rows per chunk
#define DSPLIT 4                  // w2 partial splits over d

// ---- K1: w2part[ds][i] = sum_{d in slice} fc_w[d][i] * a2[d] ----------
__global__ void k1_w2part(const float* __restrict__ fc_w,
                          const float* __restrict__ attn_w,
                          float* __restrict__ w2part) {
    int ds = blockIdx.x >> 2, is = blockIdx.x & 3;   // 16 blocks
    int i = is * 256 + threadIdx.x;
    int d0 = ds * (OUT_DIM / DSPLIT);
    float acc = 0.f;
#pragma unroll 4
    for (int d = 0; d < OUT_DIM / DSPLIT; ++d)
        acc += fc_w[(size_t)(d0 + d) * IN_DIM + i] * attn_w[OUT_DIM + d0 + d];
    w2part[ds * IN_DIM + i] = acc;
}

// ---- K2: fused single-pass over x -------------------------------------
// Per (b, chunk of R=8 rows): s2 for own rows, local max m_c, weights
// e=exp(s2-m_c), local sum, unnormalized partial ypart = sum_r e_r * x_r.
// x is staged in LDS: one HBM read total.
__global__ void __launch_bounds__(256)
k2_fused(const float* __restrict__ x,
         const float* __restrict__ w2part,
         float* __restrict__ ypart,
         float* __restrict__ mc,
         float* __restrict__ sc) {
    int b  = blockIdx.x >> 8;          // CH=256 chunks per batch
    int ch = blockIdx.x & (CH - 1);
    int t = threadIdx.x, w = t >> 6, lane = t & 63;
    __shared__ float xs[R * IN_DIM];         // 32 KB
    __shared__ float w2s[IN_DIM];            // 4 KB
    __shared__ float s2s[R];

    // sum the DSPLIT w2 partials into LDS
    {
        const float4* wp = (const float4*)w2part;
        float4 a = wp[t], b4 = wp[256 + t], c4 = wp[512 + t], d4 = wp[768 + t];
        ((float4*)w2s)[t] = make_float4(a.x + b4.x + c4.x + d4.x,
                                        a.y + b4.y + c4.y + d4.y,
                                        a.z + b4.z + c4.z + d4.z,
                                        a.w + b4.w + c4.w + d4.w);
    }
    __syncthreads();

    // phase A: load rows (global -> reg -> LDS) and dot with w2
    const float* xb = x + ((size_t)b * NROWS + ch * R) * IN_DIM;
    float4* xs4 = (float4*)xs;
    const float4* w2s4 = (const float4*)w2s;
#pragma unroll
    for (int r2 = 0; r2 < 2; ++r2) {
        int r = w * 2 + r2;
        const float4* xr = (const float4*)(xb + (size_t)r * IN_DIM);
        float acc = 0.f;
#pragma unroll
        for (int k = 0; k < 4; ++k) {
            float4 v = xr[lane + k * 64];
            float4 u = w2s4[lane + k * 64];
            xs4[r * 256 + lane + k * 64] = v;
            acc += v.x * u.x + v.y * u.y + v.z * u.z + v.w * u.w;
        }
        for (int off = 32; off; off >>= 1) acc += __shfl_down(acc, off, 64);
        if (lane == 0) s2s[r] = acc;
    }
    __syncthreads();

    // phase B: local softmax stats (redundant per thread; LDS broadcast)
    float m = -1e30f;
#pragma unroll
    for (int r = 0; r < R; ++r) m = fmaxf(m, s2s[r]);
    float e[R], s = 0.f;
#pragma unroll
    for (int r = 0; r < R; ++r) { e[r] = __expf(s2s[r] - m); s += e[r]; }
    if (t == 0) { mc[blockIdx.x] = m; sc[blockIdx.x] = s; }

    // phase C: weighted partial from LDS
    float4 acc = {0.f, 0.f, 0.f, 0.f};
#pragma unroll
    for (int r = 0; r < R; ++r) {
        float4 v = xs4[r * 256 + t];
        acc.x += e[r] * v.x; acc.y += e[r] * v.y;
        acc.z += e[r] * v.z; acc.w += e[r] * v.w;
    }
    ((float4*)ypart)[(size_t)blockIdx.x * 256 + t] = acc;
}

// ---- K3: merge chunks -> y, then c = y @ fc_w^T + fc_b ----------------
__global__ void __launch_bounds__(256)
k3_reduce_c(const float* __restrict__ ypart,
            const float* __restrict__ mc,
            const float* __restrict__ sc,
            const float* __restrict__ fc_w,
            const float* __restrict__ fc_b,
            float* __restrict__ cbuf) {
    int b = blockIdx.x >> 4, ds = blockIdx.x & 15;   // 64 blocks
    int t = threadIdx.x;
    __shared__ float red[256];
    __shared__ float f_lds[256];
    __shared__ float ys[IN_DIM];

    float mcv = mc[b * CH + t];
    red[t] = mcv; __syncthreads();
    for (int o = 128; o; o >>= 1) {
        if (t < o) red[t] = fmaxf(red[t], red[t + o]);
        __syncthreads();
    }
    float M = red[0]; __syncthreads();
    float f = __expf(mcv - M);
    f_lds[t] = f;
    red[t] = f * sc[b * CH + t]; __syncthreads();
    for (int o = 128; o; o >>= 1) {
        if (t < o) red[t] += red[t + o];
        __syncthreads();
    }
    float inv = 1.f / red[0];

    // y[i] = inv * sum_c f_c * ypart[c][i]   (thread t owns float4 i=4t..4t+3)
    float4 y = {0.f, 0.f, 0.f, 0.f};
    const float4* yp4 = (const float4*)ypart + (size_t)b * CH * 256;
#pragma unroll 4
    for (int c0 = 0; c0 < CH; ++c0) {
        float fc = f_lds[c0];
        float4 v = yp4[c0 * 256 + t];
        y.x += fc * v.x; y.y += fc * v.y; y.z += fc * v.z; y.w += fc * v.w;
    }
    y.x *= inv; y.y *= inv; y.z *= inv; y.w *= inv;
    ((float4*)ys)[t] = y;
    __syncthreads();

    // c[b][d] for 32 d-rows per block: wave-parallel dots
    int w = t >> 6, lane = t & 63;
    const float4* ys4 = (const float4*)ys;
#pragma unroll
    for (int q = 0; q < 8; ++q) {
        int d = ds * 32 + w * 8 + q;
        const float4* wr = (const float4*)(fc_w + (size_t)d * IN_DIM);
        float acc = 0.f;
#pragma unroll
        for (int k = 0; k < 4; ++k) {
            float4 a = wr[lane + k * 64];
            float4 yy = ys4[lane + k * 64];
            acc += a.x * yy.x + a.y * yy.y + a.z * yy.z + a.w * yy.w;
        }
        for (int off = 32; off; off >>= 1) acc += __shfl_down(acc, off, 64);
        if (lane == 0) cbuf[b * OUT_DIM + d] = acc + fc_b[d];
    }
}

// ---- K4: out[b,n,:] = c[b,:] broadcast --------------------------------
__global__ void k4_bcast(const float* __restrict__ cbuf,
                         float4* __restrict__ out) {
    int fi = blockIdx.x * 256 + threadIdx.x;   // 1M float4s
    int d4  = fi & 127;
    int row = fi >> 7;
    int b   = row >> 11;
    out[fi] = ((const float4*)(cbuf + (size_t)b * OUT_DIM))[d4];
}

extern "C" void kernel_launch(void* const* d_in, const int* in_sizes, int n_in,
                              void* d_out, int out_size, void* d_ws, size_t ws_size,
                              hipStream_t stream) {
    const float* x      = (const float*)d_in[0];
    const float* fc_w   = (const float*)d_in[1];
    const float* fc_b   = (const float*)d_in[2];
    const float* attn_w = (const float*)d_in[3];
    // attn_b cancels in softmax — unused.

    float* ws     = (float*)d_ws;
    float* w2part = ws;                                   // 4*1024
    float* mc     = w2part + DSPLIT * IN_DIM;             // 1024
    float* sc     = mc + BATCH * CH;                      // 1024
    float* ypart  = sc + BATCH * CH;                      // 4*256*1024 = 1 MiB
    float* cbuf   = ypart + (size_t)BATCH * CH * IN_DIM;  // 2048
    float* out    = (float*)d_out;

    k1_w2part <<<DSPLIT * 4, 256, 0, stream>>>(fc_w, attn_w, w2part);
    k2_fused  <<<BATCH * CH, 256, 0, stream>>>(x, w2part, ypart, mc, sc);
    k3_reduce_c<<<BATCH * 16, 256, 0, stream>>>(ypart, mc, sc, fc_w, fc_b, cbuf);
    k4_bcast  <<<(BATCH * NROWS * OUT_DIM / 4) / 256, 256, 0, stream>>>(cbuf, (float4*)out);
}